// Round 8
// baseline (228.502 us; speedup 1.0000x reference)
//
#include <hip/hip_runtime.h>

#define TT 16
#define CC 320
#define NHEADS 8
#define DH 64
#define INNER 512

typedef float f32x4 __attribute__((ext_vector_type(4)));
typedef float f32x16 __attribute__((ext_vector_type(16)));
typedef short bf16x8 __attribute__((ext_vector_type(8)));
typedef unsigned short u16;

#define Z16 {0.f,0.f,0.f,0.f,0.f,0.f,0.f,0.f,0.f,0.f,0.f,0.f,0.f,0.f,0.f,0.f}

__device__ __forceinline__ float bf2f(u16 u){
    union { unsigned int i; float f; } v; v.i = ((unsigned int)u) << 16; return v.f;
}
__device__ __forceinline__ u16 f2bf(float f){
    union { float f; unsigned int i; } v; v.f = f;
    unsigned int x = v.i;
    return (u16)((x + 0x7fffu + ((x >> 16) & 1u)) >> 16);   // RNE
}

// ---------------- kernel 1a: Wq/Wk/Wv fp32 -> bf16 32x32x16-frag, 12KB-CHUNK-major ----------------
// frag f = ((hd*10 + c)*6 + nblk)*2 + kl ; kk = c*2 + kl (K-step 16)
// nblk 0,1=Q  2,3=K  4,5=V (32 cols each). Within frag: lane = ((k%16)>>3)*32 + (n%32), elem=k%8.
// One chunk (c) = 12 contiguous frags = 12 KB -> linear global_load_lds staging.
__global__ __launch_bounds__(256) void k_wqkv32(const float* __restrict__ wq, const float* __restrict__ wk,
                                                const float* __restrict__ wv, u16* __restrict__ dst){
    int gid  = blockIdx.x * 256 + threadIdx.x;   // 0..61439
    int lane = gid & 63;
    int f    = gid >> 6;                          // 0..959
    int local = f % 12;
    int kl   = local & 1;
    int nblk = local >> 1;
    int c    = (f / 12) % 10;
    int hd   = f / 120;
    int kk   = c * 2 + kl;
    const float* W = (nblk < 2) ? wq : (nblk < 4) ? wk : wv;
    int n  = hd * DH + (nblk & 1) * 32 + (lane & 31);
    int k0 = kk * 16 + (lane >> 5) * 8;
    const float* src = W + (size_t)n * CC + k0;
    f32x4 v0 = *(const f32x4*)src;
    f32x4 v1 = *(const f32x4*)(src + 4);
    bf16x8 o;
    o[0] = (short)f2bf(v0[0]); o[1] = (short)f2bf(v0[1]);
    o[2] = (short)f2bf(v0[2]); o[3] = (short)f2bf(v0[3]);
    o[4] = (short)f2bf(v1[0]); o[5] = (short)f2bf(v1[1]);
    o[6] = (short)f2bf(v1[2]); o[7] = (short)f2bf(v1[3]);
    *(bf16x8*)(dst + (size_t)gid * 8) = o;
}

// ---------------- kernel 1b: Wo fp32 -> bf16 16x16x32-frag-major ----------------
__global__ __launch_bounds__(256) void k_wo16(const float* __restrict__ wo, u16* __restrict__ dst){
    int idx  = blockIdx.x * 256 + threadIdx.x;   // 20480 frag-lanes
    int lane = idx & 63;
    int blk  = idx >> 6;
    int KT = INNER / 32;
    int n  = (blk / KT) * 16 + (lane & 15);
    int k0 = (blk % KT) * 32 + (lane >> 4) * 8;
    const float* src = wo + (size_t)n * INNER + k0;
    f32x4 v0 = *(const f32x4*)src;
    f32x4 v1 = *(const f32x4*)(src + 4);
    bf16x8 o;
    o[0] = (short)f2bf(v0[0]); o[1] = (short)f2bf(v0[1]);
    o[2] = (short)f2bf(v0[2]); o[3] = (short)f2bf(v0[3]);
    o[4] = (short)f2bf(v1[0]); o[5] = (short)f2bf(v1[1]);
    o[6] = (short)f2bf(v1[2]); o[7] = (short)f2bf(v1[3]);
    *(bf16x8*)(dst + (size_t)idx * 8) = o;
}

// ---------------- kernel 2: transpose + LayerNorm -> xn bf16 32x32x16 A-frag-major ----------------
__global__ __launch_bounds__(256) void k_ln(const float* __restrict__ x, const float* __restrict__ lnw,
                                            const float* __restrict__ lnb, u16* __restrict__ xnf){
    __shared__ float tile[CC][37];
    __shared__ float psum[32][36];
    __shared__ float psq[32][36];
    __shared__ float meanb[32];
    __shared__ float rstdb[32];

    int wg = blockIdx.x;                 // (b,h,t)
    int t = wg & 15, h = (wg >> 4) & 31, b = wg >> 9;
    int tid = threadIdx.x;
    const size_t base = ((size_t)(b * CC) * TT + t) * 1024 + h * 32;

    int w4 = (tid & 7) * 4, cg = tid >> 3;
    f32x4 s4 = {0.f,0.f,0.f,0.f}, q4 = {0.f,0.f,0.f,0.f};
    for (int i = 0; i < 10; ++i){
        int c = cg * 10 + i;
        f32x4 v = *(const f32x4*)(x + base + (size_t)c * 16384 + w4);
        tile[c][w4 + 0] = v[0]; tile[c][w4 + 1] = v[1];
        tile[c][w4 + 2] = v[2]; tile[c][w4 + 3] = v[3];
        s4 += v; q4 += v * v;
    }
    psum[cg][w4 + 0] = s4[0]; psum[cg][w4 + 1] = s4[1]; psum[cg][w4 + 2] = s4[2]; psum[cg][w4 + 3] = s4[3];
    psq [cg][w4 + 0] = q4[0]; psq [cg][w4 + 1] = q4[1]; psq [cg][w4 + 2] = q4[2]; psq [cg][w4 + 3] = q4[3];
    __syncthreads();

    if (tid < 32){
        float s = 0.f, q = 0.f;
        for (int g = 0; g < 32; ++g){ s += psum[g][tid]; q += psq[g][tid]; }
        float mean = s * (1.f / CC);
        float var  = q * (1.f / CC) - mean * mean;
        meanb[tid] = mean;
        rstdb[tid] = rsqrtf(var + 1e-5f);
    }
    __syncthreads();

    int cl = tid & 63, wq_ = tid >> 6;
    float lw[5], lb[5];
    #pragma unroll
    for (int ci = 0; ci < 5; ++ci){ lw[ci] = lnw[ci * 64 + cl]; lb[ci] = lnb[ci * 64 + cl]; }
    int s_base = (b * 32 + h) * 32;
    for (int wi = 0; wi < 8; ++wi){
        int w = wq_ * 8 + wi;
        float mean = meanb[w], rstd = rstdb[w];
        int s = s_base + w;
        int row = ((s & 1) << 4) | t;
        size_t m32 = (size_t)(s >> 1);
        #pragma unroll
        for (int ci = 0; ci < 5; ++ci){
            int c = ci * 64 + cl;
            float nv = (tile[c][w] - mean) * rstd * lw[ci] + lb[ci];
            int lane = ((((c & 15) >> 3)) << 5) | row;
            xnf[((m32 * 20 + (c >> 4)) * 64 + lane) * 8 + (c & 7)] = f2bf(nv);
        }
    }
}

// ---------------- kernel 3: fused QKV + attention, LDS-staged weights ----------------
// 256 thr = 4 waves; wave owns one 32-row m-tile (2 samples), xn A-frags in regs.
// QKV: 10 chunks/head of 12KB staged via global_load_lds (double-buffered, overlaying
// qh/kh scratch which is fully rewritten per head; vt with persistent zero-pads is NOT
// overlaid). Attention: R6-verbatim per-sample 16x16 path. LDS 72KB -> 2 WG/CU.
#define QH(w,s,r,c) smem[((((w)*2+(s))*16+(r))*72) + (c)]
#define KH(w,s,r,c) smem[9216 + ((((w)*2+(s))*16+(r))*72) + (c)]
#define VT(w,s,d,k) smem[18432 + ((((w)*2+(s))*64+(d))*36) + (k)]

__global__ __launch_bounds__(256, 2) void k_attn(const u16* __restrict__ xnf,
                                                 const u16* __restrict__ wqkv,
                                                 u16* __restrict__ aof){
    // u16 indices: qh [0,9216) kh [9216,18432) vt [18432,36864)  (73,728 B total)
    // weight buffers overlay: buf0 = [0,6144), buf1 = [6144,12288)  (12KB each)
    __shared__ u16 smem[36864];

    const int tid  = threadIdx.x;
    const int lane = tid & 63;
    const int wid  = tid >> 6;        // 0..3
    const int l31  = lane & 31;
    const int h32  = lane >> 5;
    const int l15  = lane & 15;
    const int g4   = lane >> 4;
    const int m32  = blockIdx.x * 4 + wid;
    const f32x4 zero4 = {0.f, 0.f, 0.f, 0.f};

    // zero vt pad cols 16..31 once (vt region is never overlaid; per-head writes touch cols 0..15 only)
    #pragma unroll
    for (int j = 0; j < 32; ++j){
        int idx = j * 64 + lane;           // 0..2047 per wave slice
        int smp = idx >> 10;
        int d   = (idx >> 4) & 63;
        VT(wid, smp, d, 16 + (idx & 15)) = 0;
    }

    // persistent A-frags (this wave's 32 rows x 320 K), coalesced frag loads
    bf16x8 a_f[20];
    {
        const u16* xp = xnf + ((size_t)m32 * 20 * 64 + lane) * 8;
        #pragma unroll
        for (int kk = 0; kk < 20; ++kk)
            a_f[kk] = *(const bf16x8*)(xp + kk * 512);
    }

    #define STAGE(hd_, c_) do {                                                        \
        const u16* gsrc_ = wqkv + ((size_t)((hd_) * 10 + (c_)) * 6144);                \
        u16* ldst_ = (u16*)smem + ((c_) & 1) * 6144;                                   \
        _Pragma("unroll")                                                              \
        for (int i_ = 0; i_ < 3; ++i_)                                                 \
            __builtin_amdgcn_global_load_lds(                                          \
                (const __attribute__((address_space(1))) void*)(gsrc_ + (tid + i_ * 256) * 8), \
                (__attribute__((address_space(3))) void*)(ldst_ + (tid + i_ * 256) * 8),       \
                16, 0, 0);                                                             \
    } while (0)

    for (int hd = 0; hd < NHEADS; ++hd){
        // all waves done with prev head's qh/kh reads before staging clobbers them
        __builtin_amdgcn_sched_barrier(0);
        __builtin_amdgcn_s_barrier();
        __builtin_amdgcn_sched_barrier(0);

        STAGE(hd, 0);

        f32x16 acc[6];
        #pragma unroll
        for (int nb = 0; nb < 6; ++nb) acc[nb] = (f32x16)Z16;

        #pragma unroll
        for (int c = 0; c < 10; ++c){
            asm volatile("s_waitcnt vmcnt(0)" ::: "memory");
            __builtin_amdgcn_sched_barrier(0);
            __builtin_amdgcn_s_barrier();      // chunk c visible to all waves
            __builtin_amdgcn_sched_barrier(0);
            if (c < 9) STAGE(hd, c + 1);       // prefetch next chunk during compute
            const u16* wb = (const u16*)smem + (c & 1) * 6144;
            #pragma unroll
            for (int kl = 0; kl < 2; ++kl){
                #pragma unroll
                for (int nb = 0; nb < 6; ++nb){
                    bf16x8 b = *(const bf16x8*)(wb + (nb * 2 + kl) * 512 + lane * 8);
                    acc[nb] = __builtin_amdgcn_mfma_f32_32x32x16_bf16(a_f[c * 2 + kl], b, acc[nb], 0, 0, 0);
                }
            }
            __builtin_amdgcn_sched_barrier(0);
            __builtin_amdgcn_s_barrier();      // all waves done reading buf[c&1]
            __builtin_amdgcn_sched_barrier(0);
        }

        // ---- unpack QKV accumulators to wave-private LDS slices (R6-verbatim) ----
        #pragma unroll
        for (int r = 0; r < 16; ++r){
            int row = (r & 3) + 8 * (r >> 2) + 4 * h32;   // verified 32x32 C layout
            int smp = row >> 4, tr = row & 15;
            QH(wid, smp, tr, l31)      = f2bf(acc[0][r] * 0.125f);   // pre-scale 1/sqrt(64)
            QH(wid, smp, tr, 32 + l31) = f2bf(acc[1][r] * 0.125f);
            KH(wid, smp, tr, l31)      = f2bf(acc[2][r]);
            KH(wid, smp, tr, 32 + l31) = f2bf(acc[3][r]);
            VT(wid, smp, l31, tr)      = f2bf(acc[4][r]);            // V^T: [d][key16]
            VT(wid, smp, 32 + l31, tr) = f2bf(acc[5][r]);
        }

        // ---- attention, per owned sample (wave-private, R6-verbatim) ----
        #pragma unroll
        for (int smp = 0; smp < 2; ++smp){
            f32x4 sc = zero4;
            #pragma unroll
            for (int k0 = 0; k0 < DH; k0 += 32){
                bf16x8 qa = *(const bf16x8*)&QH(wid, smp, l15, k0 + g4 * 8);
                bf16x8 kb = *(const bf16x8*)&KH(wid, smp, l15, k0 + g4 * 8);
                sc = __builtin_amdgcn_mfma_f32_16x16x32_bf16(qa, kb, sc, 0, 0, 0);
            }
            f32x4 pr;
            #pragma unroll
            for (int r = 0; r < 4; ++r){
                float m = sc[r];
                m = fmaxf(m, __shfl_xor(m, 1)); m = fmaxf(m, __shfl_xor(m, 2));
                m = fmaxf(m, __shfl_xor(m, 4)); m = fmaxf(m, __shfl_xor(m, 8));
                float e = __expf(sc[r] - m);
                float ss = e;
                ss += __shfl_xor(ss, 1); ss += __shfl_xor(ss, 2);
                ss += __shfl_xor(ss, 4); ss += __shfl_xor(ss, 8);
                pr[r] = e / ss;
            }
            // P -> qh cols 0..31 (Q dead); keys 16..31 zero
            #pragma unroll
            for (int r = 0; r < 4; ++r){
                QH(wid, smp, g4 * 4 + r, l15) = f2bf(pr[r]);
                QH(wid, smp, g4 * 4 + r, 16 + l15) = 0;
            }
            // PV (K=32 zero-padded), stage into kh (dead after scores)
            bf16x8 pa = *(const bf16x8*)&QH(wid, smp, l15, g4 * 8);
            #pragma unroll
            for (int nb = 0; nb < 4; ++nb){
                bf16x8 vb = *(const bf16x8*)&VT(wid, smp, nb * 16 + l15, g4 * 8);
                f32x4 at = __builtin_amdgcn_mfma_f32_16x16x32_bf16(pa, vb, zero4, 0, 0, 0);
                #pragma unroll
                for (int r = 0; r < 4; ++r)
                    KH(wid, smp, g4 * 4 + r, nb * 16 + l15) = f2bf(at[r]);
            }
            // coalesced frag-major store of attn-out (16x16x32-frag layout for k_oproj)
            const size_t sg = (size_t)m32 * 2 + smp;
            #pragma unroll
            for (int kkl = 0; kkl < 2; ++kkl){
                bf16x8 o8 = *(const bf16x8*)&KH(wid, smp, l15, kkl * 32 + g4 * 8);
                *(bf16x8*)(aof + ((sg * 16 + hd * 2 + kkl) * 64 + lane) * 8) = o8;
            }
        }
    }
    #undef STAGE
}

// ---------------- kernel 3b: O-proj GEMM  proj[65536][320] = ao[65536][512] @ Wo^T + bo ----------
__global__ __launch_bounds__(512, 4) void k_oproj(const u16* __restrict__ aof, const u16* __restrict__ wof,
                                                  const float* __restrict__ bo, u16* __restrict__ proj){
    const int tid  = threadIdx.x;
    const int lane = tid & 63;
    const int wid  = tid >> 6;
    const int l15  = lane & 15;
    const int g4   = lane >> 4;
    const int mh   = wid >> 1;
    const int nh   = wid & 1;
    const size_t mt0 = (size_t)blockIdx.x * 8 + mh * 2;
    const size_t m0  = mt0 * 16;

    f32x4 acc[10][2];
    #pragma unroll
    for (int j = 0; j < 10; ++j){
        acc[j][0] = (f32x4){0.f,0.f,0.f,0.f};
        acc[j][1] = (f32x4){0.f,0.f,0.f,0.f};
    }

    const u16* ap = aof + (mt0 * 16 * 64 + lane) * 8;
    const u16* wp = wof + (((size_t)nh * 10 * 16) * 64 + lane) * 8;

    #pragma unroll 2
    for (int kk = 0; kk < 16; ++kk){
        bf16x8 a0 = *(const bf16x8*)(ap + kk * 512);
        bf16x8 a1 = *(const bf16x8*)(ap + (16 + kk) * 512);
        #pragma unroll
        for (int j = 0; j < 10; ++j){
            bf16x8 b = *(const bf16x8*)(wp + (j * 16 + kk) * 512);
            acc[j][0] = __builtin_amdgcn_mfma_f32_16x16x32_bf16(a0, b, acc[j][0], 0, 0, 0);
            acc[j][1] = __builtin_amdgcn_mfma_f32_16x16x32_bf16(a1, b, acc[j][1], 0, 0, 0);
        }
    }

    #pragma unroll
    for (int j = 0; j < 10; ++j){
        int c = nh * 160 + j * 16 + l15;
        float bias = bo[c];
        #pragma unroll
        for (int mb = 0; mb < 2; ++mb){
            size_t row0 = m0 + mb * 16 + g4 * 4;
            #pragma unroll
            for (int r = 0; r < 4; ++r)
                proj[(row0 + r) * CC + c] = f2bf(acc[j][mb][r] + bias);
        }
    }
}

// ---------------- kernel 4: residual + transpose back to (b,c,t,h,w) ----------------
__global__ __launch_bounds__(256) void k_res(const u16* __restrict__ proj, const float* __restrict__ x,
                                             float* __restrict__ out){
    __shared__ u16 tile[32][328];
    int wg = blockIdx.x;
    int t = wg & 15, h = (wg >> 4) & 31, b = wg >> 9;
    int tid = threadIdx.x;
    int s0 = (b * 32 + h) * 32;
    #pragma unroll
    for (int i = 0; i < 5; ++i){
        int ch = tid + 256 * i;
        int w = ch / 40, cc8 = (ch % 40) * 8;
        *(bf16x8*)(&tile[w][cc8]) = *(const bf16x8*)(proj + ((size_t)(s0 + w) * TT + t) * CC + cc8);
    }
    __syncthreads();
    int w = tid & 31, cq = tid >> 5;
    size_t base = ((size_t)(b * CC) * TT + t) * 1024 + h * 32 + w;
    for (int i = 0; i < 40; ++i){
        int c = cq * 40 + i;
        size_t idx = base + (size_t)c * 16384;
        out[idx] = x[idx] + bf2f(tile[w][c]);
    }
}

extern "C" void kernel_launch(void* const* d_in, const int* in_sizes, int n_in,
                              void* d_out, int out_size, void* d_ws, size_t ws_size,
                              hipStream_t stream){
    const float* hid = (const float*)d_in[0];
    const float* lnw = (const float*)d_in[1];
    const float* lnb = (const float*)d_in[2];
    const float* Wq  = (const float*)d_in[3];
    const float* Wk  = (const float*)d_in[4];
    const float* Wv  = (const float*)d_in[5];
    const float* Wo  = (const float*)d_in[6];
    const float* bo  = (const float*)d_in[7];

    char* ws = (char*)d_ws;
    u16* wqkv = (u16*)ws;                                   // 960 frags * 512 = 491,520 elems
    u16* wo_f = wqkv + (size_t)960 * 512;                   // 163,840 elems
    u16* ao   = wo_f + 163840;                              // 65536*512 (67 MB), 16-frag-major
    u16* xn   = ao + (size_t)65536 * INNER;                 // 65536*320 (40 MB), 32-frag-major
    u16* proj = xn;                                         // reuse: xn dead after k_attn

    k_wqkv32<<<240, 256, 0, stream>>>(Wq, Wk, Wv, wqkv);
    k_wo16  <<<80, 256, 0, stream>>>(Wo, wo_f);
    k_ln    <<<2048, 256, 0, stream>>>(hid, lnw, lnb, xn);
    k_attn  <<<512, 256, 0, stream>>>(xn, wqkv, ao);
    k_oproj <<<512, 512, 0, stream>>>(ao, wo_f, bo, proj);
    k_res   <<<2048, 256, 0, stream>>>(proj, hid, (float*)d_out);
}